// Round 1
// baseline (1419.310 us; speedup 1.0000x reference)
//
#include <hip/hip_runtime.h>
#include <cstdint>
#include <cstddef>

#define NV 200000
#define NT 800000

typedef unsigned int u32;
typedef unsigned long long u64;

// ---------------- marching-tets tables ----------------
__constant__ int c_tri[16][6] = {
  {-1,-1,-1,-1,-1,-1},{1,0,2,-1,-1,-1},{4,0,3,-1,-1,-1},{1,4,2,1,3,4},
  {3,1,5,-1,-1,-1},{2,3,0,2,5,3},{1,4,0,1,5,4},{4,2,5,-1,-1,-1},
  {4,5,2,-1,-1,-1},{4,1,0,4,5,1},{3,2,0,3,5,2},{1,3,5,-1,-1,-1},
  {4,1,2,4,3,1},{3,0,4,-1,-1,-1},{2,0,1,-1,-1,-1},{-1,-1,-1,-1,-1,-1}};
__constant__ int c_ntri[16] = {0,1,1,2,1,2,2,1,1,2,2,1,2,1,1,0};
__constant__ int c_be[12] = {0,1,0,2,0,3,1,2,1,3,2,3};

// ---------------- async global->LDS (16B per lane) ----------------
__device__ __forceinline__ void async_copy16(const float* g, float* l){
  __builtin_amdgcn_global_load_lds((const __attribute__((address_space(1))) void*)g,
                                   (__attribute__((address_space(3))) void*)l, 16, 0, 0);
}

// ---------------- fused MLP: one block = 64 rows, H lives in LDS ----------------
// thread layout: tx = tid&15 (col group), ty = tid>>4 (row group of 4 rows)
// per-thread tile: 4 rows x 16 cols; col(g,c) = g*64 + tx*4 + c  (conflict-free b128 B reads)
template<int K, bool LAST>
__device__ __forceinline__ void run_layer(
    const float* __restrict__ W, const float* __restrict__ B,
    const float* __restrict__ WF, const float* __restrict__ BF,
    float* __restrict__ sdfout, int row0,
    float (*H)[256], float (*Wt)[256], int tid, int tx, int ty)
{
  float acc[4][16];
#pragma unroll
  for (int i=0;i<4;i++)
#pragma unroll
    for (int j=0;j<16;j++) acc[i][j]=0.f;

  const int wave = tid >> 6;

#pragma unroll 1
  for (int kc=0; kc<K; kc+=16){
    const int ksz = (K-kc) < 16 ? (K-kc) : 16;
    const int nch = ksz*64;                    // float4 chunks to stage
    __syncthreads();                           // prev compute done before Wt overwrite
    for (int q0=0; q0<nch; q0+=256){
      const int q = q0 + tid;
      if (q < nch) async_copy16(W + kc*256 + q*4, ((float*)Wt) + q0*4 + wave*256);
    }
    __syncthreads();                           // vmcnt(0) drained by barrier

    float a[4][16];                            // A-hoist: 4 rows x 16 k as b128
#pragma unroll
    for (int i=0;i<4;i++){
#pragma unroll
      for (int kq=0;kq<4;kq++){
        const float4 v = *(const float4*)(&H[ty*4+i][kc+kq*4]);
        a[i][kq*4+0]=v.x; a[i][kq*4+1]=v.y; a[i][kq*4+2]=v.z; a[i][kq*4+3]=v.w;
      }
    }

    auto body=[&](int kk){
      const float4 bv0 = *(const float4*)(&Wt[kk][      tx*4]);
      const float4 bv1 = *(const float4*)(&Wt[kk][ 64 + tx*4]);
      const float4 bv2 = *(const float4*)(&Wt[kk][128 + tx*4]);
      const float4 bv3 = *(const float4*)(&Wt[kk][192 + tx*4]);
#pragma unroll
      for (int i=0;i<4;i++){
        const float av = a[i][kk];
        acc[i][0] = fmaf(av,bv0.x,acc[i][0]);  acc[i][1] = fmaf(av,bv0.y,acc[i][1]);
        acc[i][2] = fmaf(av,bv0.z,acc[i][2]);  acc[i][3] = fmaf(av,bv0.w,acc[i][3]);
        acc[i][4] = fmaf(av,bv1.x,acc[i][4]);  acc[i][5] = fmaf(av,bv1.y,acc[i][5]);
        acc[i][6] = fmaf(av,bv1.z,acc[i][6]);  acc[i][7] = fmaf(av,bv1.w,acc[i][7]);
        acc[i][8] = fmaf(av,bv2.x,acc[i][8]);  acc[i][9] = fmaf(av,bv2.y,acc[i][9]);
        acc[i][10]= fmaf(av,bv2.z,acc[i][10]); acc[i][11]= fmaf(av,bv2.w,acc[i][11]);
        acc[i][12]= fmaf(av,bv3.x,acc[i][12]); acc[i][13]= fmaf(av,bv3.y,acc[i][13]);
        acc[i][14]= fmaf(av,bv3.z,acc[i][14]); acc[i][15]= fmaf(av,bv3.w,acc[i][15]);
      }
    };

    if (ksz == 16){
#pragma unroll
      for (int kk=0;kk<16;kk++) body(kk);
    } else {
#pragma unroll
      for (int kk=0;kk<16;kk++){ if (kk < ksz) body(kk); }   // static idx, no scratch
    }
  }

  __syncthreads();                             // everyone done reading H
  if (!LAST){
#pragma unroll
    for (int g=0; g<4; g++){
      const float4 bias = *(const float4*)(&B[g*64 + tx*4]);
#pragma unroll
      for (int i=0;i<4;i++){
        float4 vv;
        vv.x = fmaxf(acc[i][4*g+0]+bias.x, 0.f);
        vv.y = fmaxf(acc[i][4*g+1]+bias.y, 0.f);
        vv.z = fmaxf(acc[i][4*g+2]+bias.z, 0.f);
        vv.w = fmaxf(acc[i][4*g+3]+bias.w, 0.f);
        *(float4*)(&H[ty*4+i][g*64+tx*4]) = vv;
      }
    }
  } else {
    // fold final 256->1 dot into the epilogue; reduce over the 16 tx lanes
    float part[4] = {0.f,0.f,0.f,0.f};
#pragma unroll
    for (int g=0; g<4; g++){
      const float4 bias = *(const float4*)(&B[g*64 + tx*4]);
      const float4 wv   = *(const float4*)(&WF[g*64 + tx*4]);
#pragma unroll
      for (int i=0;i<4;i++){
        part[i] += fmaxf(acc[i][4*g+0]+bias.x,0.f)*wv.x
                 + fmaxf(acc[i][4*g+1]+bias.y,0.f)*wv.y
                 + fmaxf(acc[i][4*g+2]+bias.z,0.f)*wv.z
                 + fmaxf(acc[i][4*g+3]+bias.w,0.f)*wv.w;
      }
    }
#pragma unroll
    for (int s=1;s<16;s<<=1){
#pragma unroll
      for (int i=0;i<4;i++) part[i] += __shfl_xor(part[i], s, 64);
    }
    if (tx==0){
      const float bias_f = BF[0];
#pragma unroll
      for (int i=0;i<4;i++) sdfout[row0 + ty*4 + i] = part[i] + bias_f;
    }
  }
}

__global__ __launch_bounds__(256,2) void mlp_sdf_kernel(
    const float* __restrict__ pos,
    const float* __restrict__ w0, const float* __restrict__ b0,
    const float* __restrict__ w1, const float* __restrict__ b1,
    const float* __restrict__ w2, const float* __restrict__ b2,
    const float* __restrict__ w3, const float* __restrict__ b3,
    const float* __restrict__ wf, const float* __restrict__ bf,
    float* __restrict__ sdf)
{
  __shared__ float H[64][256];    // 64 KiB
  __shared__ float Wt[16][256];   // 16 KiB -> 80 KiB total = 2 blocks/CU
  const int tid = threadIdx.x;
  const int tx = tid & 15, ty = tid >> 4;
  const int row0 = blockIdx.x * 64;

  // positional encoding into H[.][0..26]
  if (tid < 192){
    const int r = tid/3, d = tid - 3*r;
    const float x = pos[(row0+r)*3 + d];
    H[r][d] = x;
    float f = 3.14159265358979323846f;
#pragma unroll
    for (int i=0;i<4;i++){
      H[r][3+6*i+d] = sinf(f*x);
      H[r][6+6*i+d] = cosf(f*x);
      f *= 2.0f;
    }
  }
  // (first run_layer's staging barriers also order the encoding writes)
  run_layer<27 ,false>(w0,b0,nullptr,nullptr,nullptr,row0,H,Wt,tid,tx,ty);
  run_layer<256,false>(w1,b1,nullptr,nullptr,nullptr,row0,H,Wt,tid,tx,ty);
  run_layer<256,false>(w2,b2,nullptr,nullptr,nullptr,row0,H,Wt,tid,tx,ty);
  run_layer<256,true >(w3,b3,wf,bf,sdf,row0,H,Wt,tid,tx,ty);
}

// ---------------- block-wide inclusive scan helpers ----------------
__device__ __forceinline__ u32 block_scan_incl_u32(u32 v, u32* sh, int tid){
  sh[tid]=v; __syncthreads();
#pragma unroll
  for (int s=1;s<256;s<<=1){
    const u32 y = (tid>=s) ? sh[tid-s] : 0u;
    __syncthreads();
    sh[tid] += y;
    __syncthreads();
  }
  return sh[tid];
}

// ---------------- tet pass 1: codes, crossing-edge bucket counts, stable (n1,n2) scan ----------------
__global__ void tet_count_scan(const int* __restrict__ tet, const float* __restrict__ sdf,
    unsigned char* __restrict__ codes, u32* __restrict__ tscan, u64* __restrict__ tsum,
    u32* __restrict__ cnt)
{
  __shared__ u32 sh[256];
  const int tid = threadIdx.x;
  const int t0 = blockIdx.x*4096 + tid*16;
  int n1=0, n2=0;
#pragma unroll 1
  for (int i=0;i<16;i++){
    const int t = t0+i;
    int nt = 0;
    if (t < NT){
      tscan[t] = (u32)n1 | ((u32)n2<<16);          // thread-local exclusive (block part added later)
      const int4 v = *(const int4*)(&tet[4*t]);
      const int o0 = sdf[v.x] > 0.f;
      const int o1 = sdf[v.y] > 0.f;
      const int o2 = sdf[v.z] > 0.f;
      const int o3 = sdf[v.w] > 0.f;
      const int code = o0 | (o1<<1) | (o2<<2) | (o3<<3);
      codes[t] = (unsigned char)code;
      nt = c_ntri[code];
      if (nt > 0){
        const int vv[4] = {v.x, v.y, v.z, v.w};
        const int oc[4] = {o0,o1,o2,o3};
#pragma unroll
        for (int e=0;e<6;e++){
          const int ia = c_be[2*e], ib = c_be[2*e+1];
          if (oc[ia] != oc[ib]){
            const int p = vv[ia], q = vv[ib];
            const int lo = p<q ? p : q;
            atomicAdd(&cnt[lo], 1u);
          }
        }
      }
    }
    n1 += (nt==1);
    n2 += (nt==2);
  }
  const u32 mytot = (u32)n1 | ((u32)n2<<16);
  const u32 incl = block_scan_incl_u32(mytot, sh, tid);
  const u32 excl = incl - mytot;
#pragma unroll 1
  for (int i=0;i<16;i++){
    const int t = t0+i;
    if (t < NT) tscan[t] += excl;                  // packed add: fields stay < 65536 per block
  }
  if (tid == 255) tsum[blockIdx.x] = (u64)(incl & 0xFFFFu) | ((u64)(incl >> 16) << 32);
}

__global__ void scan_small_u64(u64* __restrict__ arr, int nb, u32* __restrict__ meta)
{
  __shared__ u64 sh[256];
  const int tid = threadIdx.x;
  const u64 v = (tid < nb) ? arr[tid] : 0ull;
  sh[tid]=v; __syncthreads();
#pragma unroll
  for (int s=1;s<256;s<<=1){ const u64 y=(tid>=s)?sh[tid-s]:0ull; __syncthreads(); sh[tid]+=y; __syncthreads(); }
  const u64 incl = sh[tid];
  if (tid < nb) arr[tid] = incl - v;
  if (tid == nb-1){ meta[0]=(u32)(incl & 0xFFFFFFFFull); meta[1]=(u32)(incl>>32); }
}

__global__ void scan_blocks_u32(const u32* __restrict__ in, u32* __restrict__ out,
                                u32* __restrict__ bsum, int n)
{
  __shared__ u32 sh[256];
  const int tid = threadIdx.x;
  const int base = blockIdx.x*4096 + tid*16;
  u32 v[16]; u32 tot=0;
#pragma unroll
  for (int i=0;i<16;i++){
    const int idx = base+i;
    v[i] = (idx<n) ? in[idx] : 0u;
    tot += v[i];
  }
  const u32 incl = block_scan_incl_u32(tot, sh, tid);
  u32 run = incl - tot;
#pragma unroll
  for (int i=0;i<16;i++){
    const int idx = base+i;
    if (idx<n) out[idx] = run;
    run += v[i];
  }
  if (tid==255) bsum[blockIdx.x] = incl;
}

__global__ void scan_small_u32(u32* __restrict__ arr, int nb, u32* __restrict__ meta, int slot)
{
  __shared__ u32 sh[256];
  const int tid = threadIdx.x;
  const u32 v = (tid<nb)?arr[tid]:0u;
  const u32 incl = block_scan_incl_u32(v, sh, tid);
  if (tid<nb) arr[tid] = incl - v;
  if (tid == nb-1) meta[slot] = incl;
}

// ---------------- scatter crossing-edge his into per-lo buckets ----------------
__global__ void fill_edges(const int* __restrict__ tet, const unsigned char* __restrict__ codes,
    const u32* __restrict__ cntE, const u32* __restrict__ bsum,
    u32* __restrict__ cur, int* __restrict__ ehi, int ecap)
{
  const int t = blockIdx.x*256 + threadIdx.x;
  if (t >= NT) return;
  const int code = codes[t];
  if (c_ntri[code] == 0) return;
  const int4 v = *(const int4*)(&tet[4*t]);
  const int vv[4]={v.x,v.y,v.z,v.w};
  const int oc[4]={code&1,(code>>1)&1,(code>>2)&1,(code>>3)&1};
#pragma unroll
  for (int e=0;e<6;e++){
    const int ia=c_be[2*e], ib=c_be[2*e+1];
    if (oc[ia]!=oc[ib]){
      const int p=vv[ia], q=vv[ib];
      const int lo = p<q?p:q, hi = p<q?q:p;
      const u32 off = bsum[lo>>12] + cntE[lo];
      const u32 slot = atomicAdd(&cur[lo],1u);
      const u32 idx = off + slot;
      if (idx < (u32)ecap) ehi[idx] = hi;
    }
  }
}

// ---------------- per-bucket sort + dedup (buckets are ~Poisson(0.12), tiny) ----------------
__global__ void sort_dedup(const u32* __restrict__ cnt, const u32* __restrict__ cntE,
    const u32* __restrict__ bsum, int* __restrict__ ehi, u32* __restrict__ ucnt, int ecap)
{
  const int lo = blockIdx.x*256 + threadIdx.x;
  if (lo >= NV) return;
  int n = (int)cnt[lo];
  const u32 off = bsum[lo>>12] + cntE[lo];
  long long rem = (long long)ecap - (long long)off;
  if (rem < 0) rem = 0;
  if ((long long)n > rem) n = (int)rem;
  for (int i=1;i<n;i++){
    const int key = ehi[off+i];
    int j=i-1;
    while (j>=0 && ehi[off+j] > key){ ehi[off+j+1]=ehi[off+j]; j--; }
    ehi[off+j+1]=key;
  }
  int u=0; int prev=-1;
  for (int i=0;i<n;i++){
    const int x = ehi[off+i];
    if (x != prev){ ehi[off+u]=x; u++; prev=x; }
  }
  ucnt[lo]=(u32)u;
}

// ---------------- emit interpolated vertices (id order == jnp.unique lex order) ----------------
__global__ void emit_verts(const float* __restrict__ pos, const float* __restrict__ sdf,
    const u32* __restrict__ ucnt, const u32* __restrict__ ubaseE, const u32* __restrict__ usum,
    const u32* __restrict__ cntE, const u32* __restrict__ bsum,
    const int* __restrict__ ehi, float* __restrict__ out, int out_size)
{
  const int lo = blockIdx.x*256 + threadIdx.x;
  if (lo >= NV) return;
  const int u = (int)ucnt[lo];
  if (u == 0) return;
  const u32 off = bsum[lo>>12] + cntE[lo];
  const u32 idbase = usum[lo>>12] + ubaseE[lo];
  const float s0 = sdf[lo];
  const float p0x = pos[3*lo], p0y = pos[3*lo+1], p0z = pos[3*lo+2];
  for (int j=0;j<u;j++){
    const int hi = ehi[off+j];
    const float s1 = sdf[hi];
    const float d = s0 - s1;
    const float vx = (p0x*(-s1) + pos[3*hi  ]*s0) / d;
    const float vy = (p0y*(-s1) + pos[3*hi+1]*s0) / d;
    const float vz = (p0z*(-s1) + pos[3*hi+2]*s0) / d;
    const long long w = 3ll*(long long)(idbase+(u32)j);
    if (w + 3 <= (long long)out_size){
      out[w]=vx; out[w+1]=vy; out[w+2]=vz;
    }
  }
}

// ---------------- emit faces: all 1-tri tets (tet order), then 2-tri tets ----------------
__global__ void emit_faces(const int* __restrict__ tet, const unsigned char* __restrict__ codes,
    const u32* __restrict__ tscan, const u64* __restrict__ tsumE, const u32* __restrict__ meta,
    const u32* __restrict__ ucnt, const u32* __restrict__ ubaseE, const u32* __restrict__ usum,
    const u32* __restrict__ cntE, const u32* __restrict__ bsum,
    const int* __restrict__ ehi, float* __restrict__ out, int out_size)
{
  const int t = blockIdx.x*256 + threadIdx.x;
  if (t >= NT) return;
  const int code = codes[t];
  const int nt = c_ntri[code];
  if (nt == 0) return;
  const u64 tb = tsumE[t>>12];
  const u32 ts = tscan[t];
  const u32 n1e = (u32)(tb & 0xFFFFFFFFull) + (ts & 0xFFFFu);
  const u32 n2e = (u32)(tb >> 32) + (ts >> 16);
  const u32 N1 = meta[0];
  const u32 M  = meta[3];
  const u32 fb = (nt==1) ? n1e : (N1 + 2u*n2e);
  const int4 v = *(const int4*)(&tet[4*t]);
  const int vv[4]={v.x,v.y,v.z,v.w};
  for (int r=0;r<nt;r++){
    for (int k=0;k<3;k++){
      const int e = c_tri[code][3*r+k];
      const int ia=c_be[2*e], ib=c_be[2*e+1];
      const int p=vv[ia], q=vv[ib];
      const int lo = p<q?p:q, hi = p<q?q:p;
      const u32 off = bsum[lo>>12] + cntE[lo];
      const int u = (int)ucnt[lo];
      int id = -1;
      for (int j=0;j<u;j++){
        if (ehi[off+j]==hi){ id = (int)(usum[lo>>12] + ubaseE[lo]) + j; break; }
      }
      const long long w = 3ll*(long long)M + 3ll*(long long)(fb+(u32)r) + k;
      if (w < (long long)out_size && id >= 0) out[w] = (float)id;  // faces stored as float values
    }
  }
}

// ---------------- launch ----------------
extern "C" void kernel_launch(void* const* d_in, const int* in_sizes, int n_in,
                              void* d_out, int out_size, void* d_ws, size_t ws_size,
                              hipStream_t stream)
{
  (void)in_sizes; (void)n_in;
  const float* pos = (const float*)d_in[0];
  const int*   tet = (const int*)d_in[1];
  const float* w0 = (const float*)d_in[2];
  const float* b0 = (const float*)d_in[3];
  const float* w1 = (const float*)d_in[4];
  const float* b1 = (const float*)d_in[5];
  const float* w2 = (const float*)d_in[6];
  const float* b2 = (const float*)d_in[7];
  const float* w3 = (const float*)d_in[8];
  const float* b3 = (const float*)d_in[9];
  const float* wf = (const float*)d_in[10];
  const float* bf = (const float*)d_in[11];
  float* out = (float*)d_out;
  char* ws = (char*)d_ws;

  float*         sdf   = (float*)(ws + 0);               // 200000 f32
  unsigned char* codes = (unsigned char*)(ws + 800000);  // 800000 u8
  u32* cnt    = (u32*)(ws + 1600000);                    // 200000 u32
  u32* cntE   = (u32*)(ws + 2400000);
  u32* ucnt   = (u32*)(ws + 3200000);
  u32* ubaseE = (u32*)(ws + 4000000);
  u32* cur    = (u32*)(ws + 4800000);
  u32* bsum   = (u32*)(ws + 5600000);                    // 64 u32 (49 used)
  u32* usum   = (u32*)(ws + 5600256);                    // 64 u32
  u32* meta   = (u32*)(ws + 5600512);                    // 16 u32
  u64* tsum   = (u64*)(ws + 5600768);                    // 256 u64 (196 used)
  u32* tscan  = (u32*)(ws + 5602816);                    // 800000 u32
  int* ehi    = (int*)(ws + 8802816);
  const long long avail = (long long)ws_size - 8802816ll;
  const int ecap = avail > 0 ? (int)((avail/4 < 2000000ll) ? avail/4 : 2000000ll) : 0;

  hipMemsetAsync(cnt, 0, 800000, stream);
  hipMemsetAsync(cur, 0, 800000, stream);

  mlp_sdf_kernel<<<3125,256,0,stream>>>(pos,w0,b0,w1,b1,w2,b2,w3,b3,wf,bf,sdf);
  tet_count_scan<<<196,256,0,stream>>>(tet,sdf,codes,tscan,tsum,cnt);
  scan_small_u64<<<1,256,0,stream>>>(tsum,196,meta);                 // meta[0]=N1, meta[1]=N2
  scan_blocks_u32<<<49,256,0,stream>>>(cnt,cntE,bsum,NV);
  scan_small_u32<<<1,256,0,stream>>>(bsum,49,meta,2);                // meta[2]=E
  fill_edges<<<3125,256,0,stream>>>(tet,codes,cntE,bsum,cur,ehi,ecap);
  sort_dedup<<<782,256,0,stream>>>(cnt,cntE,bsum,ehi,ucnt,ecap);
  scan_blocks_u32<<<49,256,0,stream>>>(ucnt,ubaseE,usum,NV);
  scan_small_u32<<<1,256,0,stream>>>(usum,49,meta,3);                // meta[3]=M
  emit_verts<<<782,256,0,stream>>>(pos,sdf,ucnt,ubaseE,usum,cntE,bsum,ehi,out,out_size);
  emit_faces<<<3125,256,0,stream>>>(tet,codes,tscan,tsum,meta,ucnt,ubaseE,usum,cntE,bsum,ehi,out,out_size);
}

// Round 2
// 864.012 us; speedup vs baseline: 1.6427x; 1.6427x over previous
//
#include <hip/hip_runtime.h>
#include <cstdint>
#include <cstddef>

#define NV 200000
#define NT 800000

typedef unsigned int u32;
typedef unsigned long long u64;
typedef unsigned short ushort_t;

typedef __attribute__((ext_vector_type(8))) short short8;
typedef __attribute__((ext_vector_type(4))) float f32x4;
#define MFMA16 __builtin_amdgcn_mfma_f32_16x16x32_bf16

// ---------------- marching-tets tables ----------------
__constant__ int c_tri[16][6] = {
  {-1,-1,-1,-1,-1,-1},{1,0,2,-1,-1,-1},{4,0,3,-1,-1,-1},{1,4,2,1,3,4},
  {3,1,5,-1,-1,-1},{2,3,0,2,5,3},{1,4,0,1,5,4},{4,2,5,-1,-1,-1},
  {4,5,2,-1,-1,-1},{4,1,0,4,5,1},{3,2,0,3,5,2},{1,3,5,-1,-1,-1},
  {4,1,2,4,3,1},{3,0,4,-1,-1,-1},{2,0,1,-1,-1,-1},{-1,-1,-1,-1,-1,-1}};
__constant__ int c_ntri[16] = {0,1,1,2,1,2,2,1,1,2,2,1,2,1,1,0};
__constant__ int c_be[12] = {0,1,0,2,0,3,1,2,1,3,2,3};

// ---------------- bf16 split helpers (RNE) ----------------
__device__ __forceinline__ ushort_t f2bf(float x){
  u32 u = __float_as_uint(x);
  u32 r = (u + 0x7fffu + ((u >> 16) & 1u)) >> 16;
  return (ushort_t)r;
}
__device__ __forceinline__ float bf2f(ushort_t b){
  return __uint_as_float(((u32)b) << 16);
}

// ---------------- weight split prep: fp32 W -> 3 bf16 planes, chunk-blocked [c][n][32k] ----------------
// layout per layer: plane p at base + p*NC*8192; element ((c*256+n)*32 + kk)
__global__ void split_weights(const float* __restrict__ w0, const float* __restrict__ w1,
                              const float* __restrict__ w2, const float* __restrict__ w3,
                              ushort_t* __restrict__ wp)
{
  const int idx = blockIdx.x*256 + threadIdx.x;   // 0..204799
  int base, NC, k, n;
  float val;
  if (idx < 8192){                                  // layer0: K=27 padded to 32
    base = 0; NC = 1; k = idx >> 8; n = idx & 255;
    val = (k < 27) ? w0[k*256 + n] : 0.f;
  } else {
    int r = idx - 8192;
    const int l = r >> 16;                          // 0..2  -> layers 1..3
    r &= 65535;
    k = r >> 8; n = r & 255; NC = 8;
    base = 24576 + l*196608;
    const float* w = (l==0) ? w1 : (l==1) ? w2 : w3;
    val = w[k*256 + n];
  }
  const ushort_t h = f2bf(val);       const float r1 = val - bf2f(h);
  const ushort_t m = f2bf(r1);        const float r2 = r1 - bf2f(m);
  const ushort_t lo = f2bf(r2);
  const int c = k >> 5, kk = k & 31;
  const int off = (c*256 + n)*32 + kk;
  const int psz = NC*8192;
  wp[base + off] = h;
  wp[base + psz + off] = m;
  wp[base + 2*psz + off] = lo;
}

// ---------------- MFMA MLP: block = 64 rows x 256 cols, 512 thr (8 waves x 32 cols) ----------------
// A (activations) in LDS as 3 bf16 planes; B (weights) via register-double-buffered global b128 loads.
// Verified layouts: A[m=lane&15][k=(lane>>4)*8+j]; B[n=lane&15][k=(lane>>4)*8+j]; C/D col=lane&15,row=(lane>>4)*4+reg.
template<int NC, bool LAST>
__device__ __forceinline__ void layer_run(
    const ushort_t* __restrict__ Wl, const float* __restrict__ Bv,
    const float* __restrict__ wfv,
    ushort_t (*Af)[64][264], float (*part)[8],
    int lane, int wv)
{
  const int l15 = lane & 15, q = lane >> 4;
  const int col0 = wv * 32;
  f32x4 acc[4][2];
#pragma unroll
  for (int i=0;i<4;i++)
#pragma unroll
    for (int j=0;j<2;j++) acc[i][j] = (f32x4){0.f,0.f,0.f,0.f};

  const ushort_t* bp = Wl + (u32)((col0 + l15)*32 + q*8);
  short8 bA[3][2], bB[3][2];

  auto loadB = [&](int c, short8 (*dst)[2]){
#pragma unroll
    for (int p=0;p<3;p++)
#pragma unroll
      for (int nt=0;nt<2;nt++)
        dst[p][nt] = *(const short8*)(bp + (p*NC + c)*8192 + nt*512);
  };
  auto compute = [&](int c, const short8 (*bb)[2]){
#pragma unroll
    for (int mt=0;mt<4;mt++){
      const ushort_t* ap = &Af[0][mt*16 + l15][c*32 + q*8];
      const short8 ah = *(const short8*)(ap);
      const short8 am = *(const short8*)(ap + 64*264);
      const short8 al = *(const short8*)(ap + 2*64*264);
#pragma unroll
      for (int nt=0;nt<2;nt++){
        f32x4 a = acc[mt][nt];
        a = MFMA16(ah, bb[0][nt], a, 0,0,0);   // h*h
        a = MFMA16(ah, bb[1][nt], a, 0,0,0);   // h*m
        a = MFMA16(am, bb[0][nt], a, 0,0,0);   // m*h
        a = MFMA16(ah, bb[2][nt], a, 0,0,0);   // h*l
        a = MFMA16(al, bb[0][nt], a, 0,0,0);   // l*h
        a = MFMA16(am, bb[1][nt], a, 0,0,0);   // m*m
        acc[mt][nt] = a;
      }
    }
  };

  loadB(0, bA);
  if (NC == 1){
    compute(0, bA);
  } else {
#pragma unroll 1
    for (int ch=0; ch<NC/2; ch++){
      const int c0 = 2*ch;
      loadB(c0+1, bB);
      compute(c0, bA);
      if (c0+2 < NC) loadB(c0+2, bA);
      compute(c0+1, bB);
    }
  }
  __syncthreads();                       // all waves done reading Af this layer

  if (!LAST){
#pragma unroll
    for (int nt=0;nt<2;nt++){
      const int col = col0 + nt*16 + l15;
      const float bias = Bv[col];
#pragma unroll
      for (int mt=0;mt<4;mt++)
#pragma unroll
        for (int reg=0;reg<4;reg++){
          const int row = mt*16 + q*4 + reg;
          const float v = fmaxf(acc[mt][nt][reg] + bias, 0.f);
          const ushort_t h = f2bf(v);   const float r1 = v - bf2f(h);
          const ushort_t m = f2bf(r1);  const float r2 = r1 - bf2f(m);
          const ushort_t lo = f2bf(r2);
          Af[0][row][col] = h; Af[1][row][col] = m; Af[2][row][col] = lo;
        }
    }
  } else {
    float pr[4][4];
#pragma unroll
    for (int mt=0;mt<4;mt++)
#pragma unroll
      for (int reg=0;reg<4;reg++) pr[mt][reg] = 0.f;
#pragma unroll
    for (int nt=0;nt<2;nt++){
      const int col = col0 + nt*16 + l15;
      const float bias = Bv[col];
      const float w = wfv[col];
#pragma unroll
      for (int mt=0;mt<4;mt++)
#pragma unroll
        for (int reg=0;reg<4;reg++)
          pr[mt][reg] += fmaxf(acc[mt][nt][reg] + bias, 0.f) * w;
    }
#pragma unroll
    for (int s=1;s<16;s<<=1)
#pragma unroll
      for (int mt=0;mt<4;mt++)
#pragma unroll
        for (int reg=0;reg<4;reg++)
          pr[mt][reg] += __shfl_xor(pr[mt][reg], s, 64);
    if (l15 == 0){
#pragma unroll
      for (int mt=0;mt<4;mt++)
#pragma unroll
        for (int reg=0;reg<4;reg++)
          part[mt*16 + q*4 + reg][wv] = pr[mt][reg];
    }
  }
  __syncthreads();                       // Af / part writes visible
}

__global__ __launch_bounds__(512,2) void mlp_mfma(
    const float* __restrict__ pos, const ushort_t* __restrict__ wp,
    const float* __restrict__ b0, const float* __restrict__ b1,
    const float* __restrict__ b2, const float* __restrict__ b3,
    const float* __restrict__ wf, const float* __restrict__ bf,
    float* __restrict__ sdf)
{
  __shared__ ushort_t Af[3][64][264];    // 101376 B: 3 bf16 split-planes of activations
  __shared__ float part[64][8];
  const int tid = threadIdx.x;
  const int lane = tid & 63, wv = tid >> 6;
  const int row0 = blockIdx.x * 64;

  // layer0 input: positional encoding (fp32, same ops as reference) + bf16x3 split, K padded 27->32
#pragma unroll
  for (int it=0; it<4; it++){
    const int idx = it*512 + tid;        // 2048 = 64 rows x 32 k
    const int r = idx & 63, f = idx >> 6;
    float val = 0.f;
    if (f < 3){
      val = pos[(row0 + r)*3 + f];
    } else if (f < 27){
      const int g = (f-3)/6, rem = (f-3)%6;
      const int d = rem % 3;
      const float x = pos[(row0 + r)*3 + d];
      const float fr = (float)(1 << g) * 3.14159265358979323846f;
      val = (rem < 3) ? sinf(fr*x) : cosf(fr*x);
    }
    const ushort_t h = f2bf(val);   const float r1 = val - bf2f(h);
    const ushort_t m = f2bf(r1);    const float r2 = r1 - bf2f(m);
    const ushort_t lo = f2bf(r2);
    Af[0][r][f] = h; Af[1][r][f] = m; Af[2][r][f] = lo;
  }
  __syncthreads();

  layer_run<1,false>(wp + 0,      b0, nullptr, Af, part, lane, wv);
  layer_run<8,false>(wp + 24576,  b1, nullptr, Af, part, lane, wv);
  layer_run<8,false>(wp + 221184, b2, nullptr, Af, part, lane, wv);
  layer_run<8,true >(wp + 417792, b3, wf,      Af, part, lane, wv);

  if (tid < 64){
    float s = 0.f;
#pragma unroll
    for (int w=0; w<8; w++) s += part[tid][w];
    sdf[row0 + tid] = s + bf[0];
  }
}

// ---------------- block-wide inclusive scan helpers ----------------
__device__ __forceinline__ u32 block_scan_incl_u32(u32 v, u32* sh, int tid){
  sh[tid]=v; __syncthreads();
#pragma unroll
  for (int s=1;s<256;s<<=1){
    const u32 y = (tid>=s) ? sh[tid-s] : 0u;
    __syncthreads();
    sh[tid] += y;
    __syncthreads();
  }
  return sh[tid];
}

// ---------------- tet pass 1: codes, crossing-edge bucket counts, stable (n1,n2) scan ----------------
__global__ void tet_count_scan(const int* __restrict__ tet, const float* __restrict__ sdf,
    unsigned char* __restrict__ codes, u32* __restrict__ tscan, u64* __restrict__ tsum,
    u32* __restrict__ cnt)
{
  __shared__ u32 sh[256];
  const int tid = threadIdx.x;
  const int t0 = blockIdx.x*4096 + tid*16;
  int n1=0, n2=0;
#pragma unroll 1
  for (int i=0;i<16;i++){
    const int t = t0+i;
    int nt = 0;
    if (t < NT){
      tscan[t] = (u32)n1 | ((u32)n2<<16);
      const int4 v = *(const int4*)(&tet[4*t]);
      const int o0 = sdf[v.x] > 0.f;
      const int o1 = sdf[v.y] > 0.f;
      const int o2 = sdf[v.z] > 0.f;
      const int o3 = sdf[v.w] > 0.f;
      const int code = o0 | (o1<<1) | (o2<<2) | (o3<<3);
      codes[t] = (unsigned char)code;
      nt = c_ntri[code];
      if (nt > 0){
        const int vv[4] = {v.x, v.y, v.z, v.w};
        const int oc[4] = {o0,o1,o2,o3};
#pragma unroll
        for (int e=0;e<6;e++){
          const int ia = c_be[2*e], ib = c_be[2*e+1];
          if (oc[ia] != oc[ib]){
            const int p = vv[ia], q = vv[ib];
            const int lo = p<q ? p : q;
            atomicAdd(&cnt[lo], 1u);
          }
        }
      }
    }
    n1 += (nt==1);
    n2 += (nt==2);
  }
  const u32 mytot = (u32)n1 | ((u32)n2<<16);
  const u32 incl = block_scan_incl_u32(mytot, sh, tid);
  const u32 excl = incl - mytot;
#pragma unroll 1
  for (int i=0;i<16;i++){
    const int t = t0+i;
    if (t < NT) tscan[t] += excl;
  }
  if (tid == 255) tsum[blockIdx.x] = (u64)(incl & 0xFFFFu) | ((u64)(incl >> 16) << 32);
}

__global__ void scan_small_u64(u64* __restrict__ arr, int nb, u32* __restrict__ meta)
{
  __shared__ u64 sh[256];
  const int tid = threadIdx.x;
  const u64 v = (tid < nb) ? arr[tid] : 0ull;
  sh[tid]=v; __syncthreads();
#pragma unroll
  for (int s=1;s<256;s<<=1){ const u64 y=(tid>=s)?sh[tid-s]:0ull; __syncthreads(); sh[tid]+=y; __syncthreads(); }
  const u64 incl = sh[tid];
  if (tid < nb) arr[tid] = incl - v;
  if (tid == nb-1){ meta[0]=(u32)(incl & 0xFFFFFFFFull); meta[1]=(u32)(incl>>32); }
}

__global__ void scan_blocks_u32(const u32* __restrict__ in, u32* __restrict__ out,
                                u32* __restrict__ bsum, int n)
{
  __shared__ u32 sh[256];
  const int tid = threadIdx.x;
  const int base = blockIdx.x*4096 + tid*16;
  u32 v[16]; u32 tot=0;
#pragma unroll
  for (int i=0;i<16;i++){
    const int idx = base+i;
    v[i] = (idx<n) ? in[idx] : 0u;
    tot += v[i];
  }
  const u32 incl = block_scan_incl_u32(tot, sh, tid);
  u32 run = incl - tot;
#pragma unroll
  for (int i=0;i<16;i++){
    const int idx = base+i;
    if (idx<n) out[idx] = run;
    run += v[i];
  }
  if (tid==255) bsum[blockIdx.x] = incl;
}

__global__ void scan_small_u32(u32* __restrict__ arr, int nb, u32* __restrict__ meta, int slot)
{
  __shared__ u32 sh[256];
  const int tid = threadIdx.x;
  const u32 v = (tid<nb)?arr[tid]:0u;
  const u32 incl = block_scan_incl_u32(v, sh, tid);
  if (tid<nb) arr[tid] = incl - v;
  if (tid == nb-1) meta[slot] = incl;
}

// ---------------- scatter crossing-edge his into per-lo buckets ----------------
__global__ void fill_edges(const int* __restrict__ tet, const unsigned char* __restrict__ codes,
    const u32* __restrict__ cntE, const u32* __restrict__ bsum,
    u32* __restrict__ cur, int* __restrict__ ehi, int ecap)
{
  const int t = blockIdx.x*256 + threadIdx.x;
  if (t >= NT) return;
  const int code = codes[t];
  if (c_ntri[code] == 0) return;
  const int4 v = *(const int4*)(&tet[4*t]);
  const int vv[4]={v.x,v.y,v.z,v.w};
  const int oc[4]={code&1,(code>>1)&1,(code>>2)&1,(code>>3)&1};
#pragma unroll
  for (int e=0;e<6;e++){
    const int ia=c_be[2*e], ib=c_be[2*e+1];
    if (oc[ia]!=oc[ib]){
      const int p=vv[ia], q=vv[ib];
      const int lo = p<q?p:q, hi = p<q?q:p;
      const u32 off = bsum[lo>>12] + cntE[lo];
      const u32 slot = atomicAdd(&cur[lo],1u);
      const u32 idx = off + slot;
      if (idx < (u32)ecap) ehi[idx] = hi;
    }
  }
}

// ---------------- per-bucket sort + dedup ----------------
__global__ void sort_dedup(const u32* __restrict__ cnt, const u32* __restrict__ cntE,
    const u32* __restrict__ bsum, int* __restrict__ ehi, u32* __restrict__ ucnt, int ecap)
{
  const int lo = blockIdx.x*256 + threadIdx.x;
  if (lo >= NV) return;
  int n = (int)cnt[lo];
  const u32 off = bsum[lo>>12] + cntE[lo];
  long long rem = (long long)ecap - (long long)off;
  if (rem < 0) rem = 0;
  if ((long long)n > rem) n = (int)rem;
  for (int i=1;i<n;i++){
    const int key = ehi[off+i];
    int j=i-1;
    while (j>=0 && ehi[off+j] > key){ ehi[off+j+1]=ehi[off+j]; j--; }
    ehi[off+j+1]=key;
  }
  int u=0; int prev=-1;
  for (int i=0;i<n;i++){
    const int x = ehi[off+i];
    if (x != prev){ ehi[off+u]=x; u++; prev=x; }
  }
  ucnt[lo]=(u32)u;
}

// ---------------- emit interpolated vertices (id order == jnp.unique lex order) ----------------
__global__ void emit_verts(const float* __restrict__ pos, const float* __restrict__ sdf,
    const u32* __restrict__ ucnt, const u32* __restrict__ ubaseE, const u32* __restrict__ usum,
    const u32* __restrict__ cntE, const u32* __restrict__ bsum,
    const int* __restrict__ ehi, float* __restrict__ out, int out_size)
{
  const int lo = blockIdx.x*256 + threadIdx.x;
  if (lo >= NV) return;
  const int u = (int)ucnt[lo];
  if (u == 0) return;
  const u32 off = bsum[lo>>12] + cntE[lo];
  const u32 idbase = usum[lo>>12] + ubaseE[lo];
  const float s0 = sdf[lo];
  const float p0x = pos[3*lo], p0y = pos[3*lo+1], p0z = pos[3*lo+2];
  for (int j=0;j<u;j++){
    const int hi = ehi[off+j];
    const float s1 = sdf[hi];
    const float d = s0 - s1;
    const float vx = (p0x*(-s1) + pos[3*hi  ]*s0) / d;
    const float vy = (p0y*(-s1) + pos[3*hi+1]*s0) / d;
    const float vz = (p0z*(-s1) + pos[3*hi+2]*s0) / d;
    const long long w = 3ll*(long long)(idbase+(u32)j);
    if (w + 3 <= (long long)out_size){
      out[w]=vx; out[w+1]=vy; out[w+2]=vz;
    }
  }
}

// ---------------- emit faces: all 1-tri tets (tet order), then 2-tri tets ----------------
__global__ void emit_faces(const int* __restrict__ tet, const unsigned char* __restrict__ codes,
    const u32* __restrict__ tscan, const u64* __restrict__ tsumE, const u32* __restrict__ meta,
    const u32* __restrict__ ucnt, const u32* __restrict__ ubaseE, const u32* __restrict__ usum,
    const u32* __restrict__ cntE, const u32* __restrict__ bsum,
    const int* __restrict__ ehi, float* __restrict__ out, int out_size)
{
  const int t = blockIdx.x*256 + threadIdx.x;
  if (t >= NT) return;
  const int code = codes[t];
  const int nt = c_ntri[code];
  if (nt == 0) return;
  const u64 tb = tsumE[t>>12];
  const u32 ts = tscan[t];
  const u32 n1e = (u32)(tb & 0xFFFFFFFFull) + (ts & 0xFFFFu);
  const u32 n2e = (u32)(tb >> 32) + (ts >> 16);
  const u32 N1 = meta[0];
  const u32 M  = meta[3];
  const u32 fb = (nt==1) ? n1e : (N1 + 2u*n2e);
  const int4 v = *(const int4*)(&tet[4*t]);
  const int vv[4]={v.x,v.y,v.z,v.w};
  for (int r=0;r<nt;r++){
    for (int k=0;k<3;k++){
      const int e = c_tri[code][3*r+k];
      const int ia=c_be[2*e], ib=c_be[2*e+1];
      const int p=vv[ia], q=vv[ib];
      const int lo = p<q?p:q, hi = p<q?q:p;
      const u32 off = bsum[lo>>12] + cntE[lo];
      const int u = (int)ucnt[lo];
      int id = -1;
      for (int j=0;j<u;j++){
        if (ehi[off+j]==hi){ id = (int)(usum[lo>>12] + ubaseE[lo]) + j; break; }
      }
      const long long w = 3ll*(long long)M + 3ll*(long long)(fb+(u32)r) + k;
      if (w < (long long)out_size && id >= 0) out[w] = (float)id;
    }
  }
}

// ---------------- launch ----------------
extern "C" void kernel_launch(void* const* d_in, const int* in_sizes, int n_in,
                              void* d_out, int out_size, void* d_ws, size_t ws_size,
                              hipStream_t stream)
{
  (void)in_sizes; (void)n_in;
  const float* pos = (const float*)d_in[0];
  const int*   tet = (const int*)d_in[1];
  const float* w0 = (const float*)d_in[2];
  const float* b0 = (const float*)d_in[3];
  const float* w1 = (const float*)d_in[4];
  const float* b1 = (const float*)d_in[5];
  const float* w2 = (const float*)d_in[6];
  const float* b2 = (const float*)d_in[7];
  const float* w3 = (const float*)d_in[8];
  const float* b3 = (const float*)d_in[9];
  const float* wf = (const float*)d_in[10];
  const float* bf = (const float*)d_in[11];
  float* out = (float*)d_out;
  char* ws = (char*)d_ws;

  float*         sdf   = (float*)(ws + 0);               // 200000 f32
  unsigned char* codes = (unsigned char*)(ws + 800000);  // 800000 u8
  u32* cnt    = (u32*)(ws + 1600000);                    // 200000 u32
  u32* cntE   = (u32*)(ws + 2400000);
  u32* ucnt   = (u32*)(ws + 3200000);
  u32* ubaseE = (u32*)(ws + 4000000);
  u32* cur    = (u32*)(ws + 4800000);
  u32* bsum   = (u32*)(ws + 5600000);                    // 64 u32 (49 used)
  u32* usum   = (u32*)(ws + 5600256);                    // 64 u32
  u32* meta   = (u32*)(ws + 5600512);                    // 16 u32
  u64* tsum   = (u64*)(ws + 5600768);                    // 256 u64 (196 used)
  u32* tscan  = (u32*)(ws + 5602816);                    // 800000 u32
  ushort_t* wp = (ushort_t*)(ws + 8802816);              // 614400 u16 = 1228800 B weight planes
  int* ehi    = (int*)(ws + 10031616);
  const long long avail = (long long)ws_size - 10031616ll;
  const int ecap = avail > 0 ? (int)((avail/4 < 500000ll) ? avail/4 : 500000ll) : 0;

  hipMemsetAsync(cnt, 0, 800000, stream);
  hipMemsetAsync(cur, 0, 800000, stream);

  split_weights<<<800,256,0,stream>>>(w0,w1,w2,w3,wp);
  mlp_mfma<<<3125,512,0,stream>>>(pos,wp,b0,b1,b2,b3,wf,bf,sdf);

  tet_count_scan<<<196,256,0,stream>>>(tet,sdf,codes,tscan,tsum,cnt);
  scan_small_u64<<<1,256,0,stream>>>(tsum,196,meta);                 // meta[0]=N1, meta[1]=N2
  scan_blocks_u32<<<49,256,0,stream>>>(cnt,cntE,bsum,NV);
  scan_small_u32<<<1,256,0,stream>>>(bsum,49,meta,2);                // meta[2]=E
  fill_edges<<<3125,256,0,stream>>>(tet,codes,cntE,bsum,cur,ehi,ecap);
  sort_dedup<<<782,256,0,stream>>>(cnt,cntE,bsum,ehi,ucnt,ecap);
  scan_blocks_u32<<<49,256,0,stream>>>(ucnt,ubaseE,usum,NV);
  scan_small_u32<<<1,256,0,stream>>>(usum,49,meta,3);                // meta[3]=M
  emit_verts<<<782,256,0,stream>>>(pos,sdf,ucnt,ubaseE,usum,cntE,bsum,ehi,out,out_size);
  emit_faces<<<3125,256,0,stream>>>(tet,codes,tscan,tsum,meta,ucnt,ubaseE,usum,cntE,bsum,ehi,out,out_size);
}

// Round 3
// 822.280 us; speedup vs baseline: 1.7261x; 1.0508x over previous
//
#include <hip/hip_runtime.h>
#include <cstdint>
#include <cstddef>

#define NV 200000
#define NT 800000
#define ROWS 48
#define NBLK 4167   // ceil(200000/48), 4167*48 = 200016 (tail guarded)

typedef unsigned int u32;
typedef unsigned long long u64;
typedef unsigned short ushort_t;

typedef __attribute__((ext_vector_type(8))) short short8;
typedef __attribute__((ext_vector_type(4))) float f32x4;
#define MFMA16 __builtin_amdgcn_mfma_f32_16x16x32_bf16

// ---------------- marching-tets tables ----------------
__constant__ int c_tri[16][6] = {
  {-1,-1,-1,-1,-1,-1},{1,0,2,-1,-1,-1},{4,0,3,-1,-1,-1},{1,4,2,1,3,4},
  {3,1,5,-1,-1,-1},{2,3,0,2,5,3},{1,4,0,1,5,4},{4,2,5,-1,-1,-1},
  {4,5,2,-1,-1,-1},{4,1,0,4,5,1},{3,2,0,3,5,2},{1,3,5,-1,-1,-1},
  {4,1,2,4,3,1},{3,0,4,-1,-1,-1},{2,0,1,-1,-1,-1},{-1,-1,-1,-1,-1,-1}};
__constant__ int c_ntri[16] = {0,1,1,2,1,2,2,1,1,2,2,1,2,1,1,0};
__constant__ int c_be[12] = {0,1,0,2,0,3,1,2,1,3,2,3};

// ---------------- bf16 split helpers ----------------
// RNE (used in one-shot weight prep)
__device__ __forceinline__ ushort_t f2bf(float x){
  u32 u = __float_as_uint(x);
  u32 r = (u + 0x7fffu + ((u >> 16) & 1u)) >> 16;
  return (ushort_t)r;
}
__device__ __forceinline__ float bf2f(ushort_t b){
  return __uint_as_float(((u32)b) << 16);
}
// Truncation-based 3-way split (self-correcting: h+m+l reconstructs x to ~2^-24 rel)
__device__ __forceinline__ void split3(float x, ushort_t& h, ushort_t& m, ushort_t& l){
  const u32 u  = __float_as_uint(x);
  const float hf = __uint_as_float(u & 0xffff0000u);
  h = (ushort_t)(u >> 16);
  const float r1 = x - hf;
  const u32 u1 = __float_as_uint(r1);
  const float mf = __uint_as_float(u1 & 0xffff0000u);
  m = (ushort_t)(u1 >> 16);
  const float r2 = r1 - mf;
  l = (ushort_t)(__float_as_uint(r2) >> 16);
}

// ---------------- weight split prep: fp32 W -> 3 bf16 planes, chunk-blocked [c][n][32k] ----------------
__global__ void split_weights(const float* __restrict__ w0, const float* __restrict__ w1,
                              const float* __restrict__ w2, const float* __restrict__ w3,
                              ushort_t* __restrict__ wp)
{
  const int idx = blockIdx.x*256 + threadIdx.x;   // 0..204799
  int base, NC, k, n;
  float val;
  if (idx < 8192){                                  // layer0: K=27 padded to 32
    base = 0; NC = 1; k = idx >> 8; n = idx & 255;
    val = (k < 27) ? w0[k*256 + n] : 0.f;
  } else {
    int r = idx - 8192;
    const int l = r >> 16;                          // 0..2  -> layers 1..3
    r &= 65535;
    k = r >> 8; n = r & 255; NC = 8;
    base = 24576 + l*196608;
    const float* w = (l==0) ? w1 : (l==1) ? w2 : w3;
    val = w[k*256 + n];
  }
  const ushort_t h = f2bf(val);       const float r1 = val - bf2f(h);
  const ushort_t m = f2bf(r1);        const float r2 = r1 - bf2f(m);
  const ushort_t lo = f2bf(r2);
  const int c = k >> 5, kk = k & 31;
  const int off = (c*256 + n)*32 + kk;
  const int psz = NC*8192;
  wp[base + off] = h;
  wp[base + psz + off] = m;
  wp[base + 2*psz + off] = lo;
}

// ---------------- MFMA MLP: block = 48 rows x 256 cols, 512 thr (8 waves x 32 cols) ----------------
// 2 blocks/CU (LDS 77.5 KB, VGPR capped by __launch_bounds__(512,4)).
// Verified layouts: A[m=lane&15][k=(lane>>4)*8+j]; B[n=lane&15][k=(lane>>4)*8+j]; C/D col=lane&15,row=(lane>>4)*4+reg.
template<int NC, bool LAST>
__device__ __forceinline__ void layer_run(
    const ushort_t* __restrict__ Wl, const float* __restrict__ Bv,
    const float* __restrict__ wfv,
    ushort_t (*Af)[ROWS][264], float (*part)[8],
    int lane, int wv)
{
  const int l15 = lane & 15, q = lane >> 4;
  const int col0 = wv * 32;
  f32x4 acc[3][2];
#pragma unroll
  for (int i=0;i<3;i++)
#pragma unroll
    for (int j=0;j<2;j++) acc[i][j] = (f32x4){0.f,0.f,0.f,0.f};

  const ushort_t* bp = Wl + (u32)((col0 + l15)*32 + q*8);
  short8 bA[3][2], bB[3][2];

  auto loadB = [&](int c, short8 (*dst)[2]){
#pragma unroll
    for (int p=0;p<3;p++)
#pragma unroll
      for (int nt=0;nt<2;nt++)
        dst[p][nt] = *(const short8*)(bp + (p*NC + c)*8192 + nt*512);
  };
  auto compute = [&](int c, const short8 (*bb)[2]){
#pragma unroll
    for (int mt=0;mt<3;mt++){
      const ushort_t* ap = &Af[0][mt*16 + l15][c*32 + q*8];
      const short8 ah = *(const short8*)(ap);
      const short8 am = *(const short8*)(ap + ROWS*264);
      const short8 al = *(const short8*)(ap + 2*ROWS*264);
#pragma unroll
      for (int nt=0;nt<2;nt++){
        f32x4 a = acc[mt][nt];
        a = MFMA16(ah, bb[0][nt], a, 0,0,0);   // h*h
        a = MFMA16(ah, bb[1][nt], a, 0,0,0);   // h*m
        a = MFMA16(am, bb[0][nt], a, 0,0,0);   // m*h
        a = MFMA16(ah, bb[2][nt], a, 0,0,0);   // h*l
        a = MFMA16(al, bb[0][nt], a, 0,0,0);   // l*h
        a = MFMA16(am, bb[1][nt], a, 0,0,0);   // m*m
        acc[mt][nt] = a;
      }
    }
  };

  loadB(0, bA);
  if (NC == 1){
    compute(0, bA);
  } else {
#pragma unroll 1
    for (int ch=0; ch<NC/2; ch++){
      const int c0 = 2*ch;
      loadB(c0+1, bB);
      compute(c0, bA);
      if (c0+2 < NC) loadB(c0+2, bA);
      compute(c0+1, bB);
    }
  }
  __syncthreads();                       // all waves done reading Af this layer

  if (!LAST){
#pragma unroll
    for (int nt=0;nt<2;nt++){
      const int col = col0 + nt*16 + l15;
      const float bias = Bv[col];
#pragma unroll
      for (int mt=0;mt<3;mt++)
#pragma unroll
        for (int reg=0;reg<4;reg++){
          const int row = mt*16 + q*4 + reg;
          const float v = fmaxf(acc[mt][nt][reg] + bias, 0.f);
          ushort_t h,m,l; split3(v,h,m,l);
          Af[0][row][col] = h; Af[1][row][col] = m; Af[2][row][col] = l;
        }
    }
  } else {
    float pr[3][4];
#pragma unroll
    for (int mt=0;mt<3;mt++)
#pragma unroll
      for (int reg=0;reg<4;reg++) pr[mt][reg] = 0.f;
#pragma unroll
    for (int nt=0;nt<2;nt++){
      const int col = col0 + nt*16 + l15;
      const float bias = Bv[col];
      const float w = wfv[col];
#pragma unroll
      for (int mt=0;mt<3;mt++)
#pragma unroll
        for (int reg=0;reg<4;reg++)
          pr[mt][reg] += fmaxf(acc[mt][nt][reg] + bias, 0.f) * w;
    }
#pragma unroll
    for (int s=1;s<16;s<<=1)
#pragma unroll
      for (int mt=0;mt<3;mt++)
#pragma unroll
        for (int reg=0;reg<4;reg++)
          pr[mt][reg] += __shfl_xor(pr[mt][reg], s, 64);
    if (l15 == 0){
#pragma unroll
      for (int mt=0;mt<3;mt++)
#pragma unroll
        for (int reg=0;reg<4;reg++)
          part[mt*16 + q*4 + reg][wv] = pr[mt][reg];
    }
  }
  __syncthreads();                       // Af / part writes visible
}

__global__ __launch_bounds__(512,4) void mlp_mfma(
    const float* __restrict__ pos, const ushort_t* __restrict__ wp,
    const float* __restrict__ b0, const float* __restrict__ b1,
    const float* __restrict__ b2, const float* __restrict__ b3,
    const float* __restrict__ wf, const float* __restrict__ bf,
    float* __restrict__ sdf)
{
  __shared__ ushort_t Af[3][ROWS][264];    // 76,032 B
  __shared__ float part[ROWS][8];          // 1,536 B -> 77.5 KB total = 2 blocks/CU
  const int tid = threadIdx.x;
  const int lane = tid & 63, wv = tid >> 6;
  const int row0 = blockIdx.x * ROWS;

  // layer0 input: positional encoding + trunc bf16x3 split, K padded 27->32
#pragma unroll
  for (int it=0; it<3; it++){
    const int idx = it*512 + tid;        // 1536 = 48 rows x 32 k
    const int r = idx % ROWS, f = idx / ROWS;
    const int grow = row0 + r;
    float val = 0.f;
    if (f < 3){
      val = (grow < NV) ? pos[grow*3 + f] : 0.f;
    } else if (f < 27){
      const int g = (f-3)/6, rem = (f-3)%6;
      const int d = rem % 3;
      const float x = (grow < NV) ? pos[grow*3 + d] : 0.f;
      const float fr = (float)(1 << g) * 3.14159265358979323846f;
      val = (rem < 3) ? sinf(fr*x) : cosf(fr*x);
    }
    ushort_t h,m,l; split3(val,h,m,l);
    Af[0][r][f] = h; Af[1][r][f] = m; Af[2][r][f] = l;
  }
  __syncthreads();

  layer_run<1,false>(wp + 0,      b0, nullptr, Af, part, lane, wv);
  layer_run<8,false>(wp + 24576,  b1, nullptr, Af, part, lane, wv);
  layer_run<8,false>(wp + 221184, b2, nullptr, Af, part, lane, wv);
  layer_run<8,true >(wp + 417792, b3, wf,      Af, part, lane, wv);

  if (tid < ROWS && row0 + tid < NV){
    float s = 0.f;
#pragma unroll
    for (int w=0; w<8; w++) s += part[tid][w];
    sdf[row0 + tid] = s + bf[0];
  }
}

// ---------------- block-wide inclusive scan helpers ----------------
__device__ __forceinline__ u32 block_scan_incl_u32(u32 v, u32* sh, int tid){
  sh[tid]=v; __syncthreads();
#pragma unroll
  for (int s=1;s<256;s<<=1){
    const u32 y = (tid>=s) ? sh[tid-s] : 0u;
    __syncthreads();
    sh[tid] += y;
    __syncthreads();
  }
  return sh[tid];
}

// ---------------- tet pass 1: codes, crossing-edge bucket counts, stable (n1,n2) scan ----------------
__global__ void tet_count_scan(const int* __restrict__ tet, const float* __restrict__ sdf,
    unsigned char* __restrict__ codes, u32* __restrict__ tscan, u64* __restrict__ tsum,
    u32* __restrict__ cnt)
{
  __shared__ u32 sh[256];
  const int tid = threadIdx.x;
  const int t0 = blockIdx.x*4096 + tid*16;
  int n1=0, n2=0;
#pragma unroll 1
  for (int i=0;i<16;i++){
    const int t = t0+i;
    int nt = 0;
    if (t < NT){
      tscan[t] = (u32)n1 | ((u32)n2<<16);
      const int4 v = *(const int4*)(&tet[4*t]);
      const int o0 = sdf[v.x] > 0.f;
      const int o1 = sdf[v.y] > 0.f;
      const int o2 = sdf[v.z] > 0.f;
      const int o3 = sdf[v.w] > 0.f;
      const int code = o0 | (o1<<1) | (o2<<2) | (o3<<3);
      codes[t] = (unsigned char)code;
      nt = c_ntri[code];
      if (nt > 0){
        const int vv[4] = {v.x, v.y, v.z, v.w};
        const int oc[4] = {o0,o1,o2,o3};
#pragma unroll
        for (int e=0;e<6;e++){
          const int ia = c_be[2*e], ib = c_be[2*e+1];
          if (oc[ia] != oc[ib]){
            const int p = vv[ia], q = vv[ib];
            const int lo = p<q ? p : q;
            atomicAdd(&cnt[lo], 1u);
          }
        }
      }
    }
    n1 += (nt==1);
    n2 += (nt==2);
  }
  const u32 mytot = (u32)n1 | ((u32)n2<<16);
  const u32 incl = block_scan_incl_u32(mytot, sh, tid);
  const u32 excl = incl - mytot;
#pragma unroll 1
  for (int i=0;i<16;i++){
    const int t = t0+i;
    if (t < NT) tscan[t] += excl;
  }
  if (tid == 255) tsum[blockIdx.x] = (u64)(incl & 0xFFFFu) | ((u64)(incl >> 16) << 32);
}

__global__ void scan_small_u64(u64* __restrict__ arr, int nb, u32* __restrict__ meta)
{
  __shared__ u64 sh[256];
  const int tid = threadIdx.x;
  const u64 v = (tid < nb) ? arr[tid] : 0ull;
  sh[tid]=v; __syncthreads();
#pragma unroll
  for (int s=1;s<256;s<<=1){ const u64 y=(tid>=s)?sh[tid-s]:0ull; __syncthreads(); sh[tid]+=y; __syncthreads(); }
  const u64 incl = sh[tid];
  if (tid < nb) arr[tid] = incl - v;
  if (tid == nb-1){ meta[0]=(u32)(incl & 0xFFFFFFFFull); meta[1]=(u32)(incl>>32); }
}

__global__ void scan_blocks_u32(const u32* __restrict__ in, u32* __restrict__ out,
                                u32* __restrict__ bsum, int n)
{
  __shared__ u32 sh[256];
  const int tid = threadIdx.x;
  const int base = blockIdx.x*4096 + tid*16;
  u32 v[16]; u32 tot=0;
#pragma unroll
  for (int i=0;i<16;i++){
    const int idx = base+i;
    v[i] = (idx<n) ? in[idx] : 0u;
    tot += v[i];
  }
  const u32 incl = block_scan_incl_u32(tot, sh, tid);
  u32 run = incl - tot;
#pragma unroll
  for (int i=0;i<16;i++){
    const int idx = base+i;
    if (idx<n) out[idx] = run;
    run += v[i];
  }
  if (tid==255) bsum[blockIdx.x] = incl;
}

__global__ void scan_small_u32(u32* __restrict__ arr, int nb, u32* __restrict__ meta, int slot)
{
  __shared__ u32 sh[256];
  const int tid = threadIdx.x;
  const u32 v = (tid<nb)?arr[tid]:0u;
  const u32 incl = block_scan_incl_u32(v, sh, tid);
  if (tid<nb) arr[tid] = incl - v;
  if (tid == nb-1) meta[slot] = incl;
}

// ---------------- scatter crossing-edge his into per-lo buckets ----------------
__global__ void fill_edges(const int* __restrict__ tet, const unsigned char* __restrict__ codes,
    const u32* __restrict__ cntE, const u32* __restrict__ bsum,
    u32* __restrict__ cur, int* __restrict__ ehi, int ecap)
{
  const int t = blockIdx.x*256 + threadIdx.x;
  if (t >= NT) return;
  const int code = codes[t];
  if (c_ntri[code] == 0) return;
  const int4 v = *(const int4*)(&tet[4*t]);
  const int vv[4]={v.x,v.y,v.z,v.w};
  const int oc[4]={code&1,(code>>1)&1,(code>>2)&1,(code>>3)&1};
#pragma unroll
  for (int e=0;e<6;e++){
    const int ia=c_be[2*e], ib=c_be[2*e+1];
    if (oc[ia]!=oc[ib]){
      const int p=vv[ia], q=vv[ib];
      const int lo = p<q?p:q, hi = p<q?q:p;
      const u32 off = bsum[lo>>12] + cntE[lo];
      const u32 slot = atomicAdd(&cur[lo],1u);
      const u32 idx = off + slot;
      if (idx < (u32)ecap) ehi[idx] = hi;
    }
  }
}

// ---------------- per-bucket sort + dedup ----------------
__global__ void sort_dedup(const u32* __restrict__ cnt, const u32* __restrict__ cntE,
    const u32* __restrict__ bsum, int* __restrict__ ehi, u32* __restrict__ ucnt, int ecap)
{
  const int lo = blockIdx.x*256 + threadIdx.x;
  if (lo >= NV) return;
  int n = (int)cnt[lo];
  const u32 off = bsum[lo>>12] + cntE[lo];
  long long rem = (long long)ecap - (long long)off;
  if (rem < 0) rem = 0;
  if ((long long)n > rem) n = (int)rem;
  for (int i=1;i<n;i++){
    const int key = ehi[off+i];
    int j=i-1;
    while (j>=0 && ehi[off+j] > key){ ehi[off+j+1]=ehi[off+j]; j--; }
    ehi[off+j+1]=key;
  }
  int u=0; int prev=-1;
  for (int i=0;i<n;i++){
    const int x = ehi[off+i];
    if (x != prev){ ehi[off+u]=x; u++; prev=x; }
  }
  ucnt[lo]=(u32)u;
}

// ---------------- emit interpolated vertices (id order == jnp.unique lex order) ----------------
__global__ void emit_verts(const float* __restrict__ pos, const float* __restrict__ sdf,
    const u32* __restrict__ ucnt, const u32* __restrict__ ubaseE, const u32* __restrict__ usum,
    const u32* __restrict__ cntE, const u32* __restrict__ bsum,
    const int* __restrict__ ehi, float* __restrict__ out, int out_size)
{
  const int lo = blockIdx.x*256 + threadIdx.x;
  if (lo >= NV) return;
  const int u = (int)ucnt[lo];
  if (u == 0) return;
  const u32 off = bsum[lo>>12] + cntE[lo];
  const u32 idbase = usum[lo>>12] + ubaseE[lo];
  const float s0 = sdf[lo];
  const float p0x = pos[3*lo], p0y = pos[3*lo+1], p0z = pos[3*lo+2];
  for (int j=0;j<u;j++){
    const int hi = ehi[off+j];
    const float s1 = sdf[hi];
    const float d = s0 - s1;
    const float vx = (p0x*(-s1) + pos[3*hi  ]*s0) / d;
    const float vy = (p0y*(-s1) + pos[3*hi+1]*s0) / d;
    const float vz = (p0z*(-s1) + pos[3*hi+2]*s0) / d;
    const long long w = 3ll*(long long)(idbase+(u32)j);
    if (w + 3 <= (long long)out_size){
      out[w]=vx; out[w+1]=vy; out[w+2]=vz;
    }
  }
}

// ---------------- emit faces: all 1-tri tets (tet order), then 2-tri tets ----------------
__global__ void emit_faces(const int* __restrict__ tet, const unsigned char* __restrict__ codes,
    const u32* __restrict__ tscan, const u64* __restrict__ tsumE, const u32* __restrict__ meta,
    const u32* __restrict__ ucnt, const u32* __restrict__ ubaseE, const u32* __restrict__ usum,
    const u32* __restrict__ cntE, const u32* __restrict__ bsum,
    const int* __restrict__ ehi, float* __restrict__ out, int out_size)
{
  const int t = blockIdx.x*256 + threadIdx.x;
  if (t >= NT) return;
  const int code = codes[t];
  const int nt = c_ntri[code];
  if (nt == 0) return;
  const u64 tb = tsumE[t>>12];
  const u32 ts = tscan[t];
  const u32 n1e = (u32)(tb & 0xFFFFFFFFull) + (ts & 0xFFFFu);
  const u32 n2e = (u32)(tb >> 32) + (ts >> 16);
  const u32 N1 = meta[0];
  const u32 M  = meta[3];
  const u32 fb = (nt==1) ? n1e : (N1 + 2u*n2e);
  const int4 v = *(const int4*)(&tet[4*t]);
  const int vv[4]={v.x,v.y,v.z,v.w};
  for (int r=0;r<nt;r++){
    for (int k=0;k<3;k++){
      const int e = c_tri[code][3*r+k];
      const int ia=c_be[2*e], ib=c_be[2*e+1];
      const int p=vv[ia], q=vv[ib];
      const int lo = p<q?p:q, hi = p<q?q:p;
      const u32 off = bsum[lo>>12] + cntE[lo];
      const int u = (int)ucnt[lo];
      int id = -1;
      for (int j=0;j<u;j++){
        if (ehi[off+j]==hi){ id = (int)(usum[lo>>12] + ubaseE[lo]) + j; break; }
      }
      const long long w = 3ll*(long long)M + 3ll*(long long)(fb+(u32)r) + k;
      if (w < (long long)out_size && id >= 0) out[w] = (float)id;
    }
  }
}

// ---------------- launch ----------------
extern "C" void kernel_launch(void* const* d_in, const int* in_sizes, int n_in,
                              void* d_out, int out_size, void* d_ws, size_t ws_size,
                              hipStream_t stream)
{
  (void)in_sizes; (void)n_in;
  const float* pos = (const float*)d_in[0];
  const int*   tet = (const int*)d_in[1];
  const float* w0 = (const float*)d_in[2];
  const float* b0 = (const float*)d_in[3];
  const float* w1 = (const float*)d_in[4];
  const float* b1 = (const float*)d_in[5];
  const float* w2 = (const float*)d_in[6];
  const float* b2 = (const float*)d_in[7];
  const float* w3 = (const float*)d_in[8];
  const float* b3 = (const float*)d_in[9];
  const float* wf = (const float*)d_in[10];
  const float* bf = (const float*)d_in[11];
  float* out = (float*)d_out;
  char* ws = (char*)d_ws;

  float*         sdf   = (float*)(ws + 0);               // 200000 f32
  unsigned char* codes = (unsigned char*)(ws + 800000);  // 800000 u8
  u32* cnt    = (u32*)(ws + 1600000);                    // 200000 u32
  u32* cntE   = (u32*)(ws + 2400000);
  u32* ucnt   = (u32*)(ws + 3200000);
  u32* ubaseE = (u32*)(ws + 4000000);
  u32* cur    = (u32*)(ws + 4800000);
  u32* bsum   = (u32*)(ws + 5600000);                    // 64 u32 (49 used)
  u32* usum   = (u32*)(ws + 5600256);                    // 64 u32
  u32* meta   = (u32*)(ws + 5600512);                    // 16 u32
  u64* tsum   = (u64*)(ws + 5600768);                    // 256 u64 (196 used)
  u32* tscan  = (u32*)(ws + 5602816);                    // 800000 u32
  ushort_t* wp = (ushort_t*)(ws + 8802816);              // 614400 u16 = 1228800 B weight planes
  int* ehi    = (int*)(ws + 10031616);
  const long long avail = (long long)ws_size - 10031616ll;
  const int ecap = avail > 0 ? (int)((avail/4 < 500000ll) ? avail/4 : 500000ll) : 0;

  hipMemsetAsync(cnt, 0, 800000, stream);
  hipMemsetAsync(cur, 0, 800000, stream);

  split_weights<<<800,256,0,stream>>>(w0,w1,w2,w3,wp);
  mlp_mfma<<<NBLK,512,0,stream>>>(pos,wp,b0,b1,b2,b3,wf,bf,sdf);

  tet_count_scan<<<196,256,0,stream>>>(tet,sdf,codes,tscan,tsum,cnt);
  scan_small_u64<<<1,256,0,stream>>>(tsum,196,meta);                 // meta[0]=N1, meta[1]=N2
  scan_blocks_u32<<<49,256,0,stream>>>(cnt,cntE,bsum,NV);
  scan_small_u32<<<1,256,0,stream>>>(bsum,49,meta,2);                // meta[2]=E
  fill_edges<<<3125,256,0,stream>>>(tet,codes,cntE,bsum,cur,ehi,ecap);
  sort_dedup<<<782,256,0,stream>>>(cnt,cntE,bsum,ehi,ucnt,ecap);
  scan_blocks_u32<<<49,256,0,stream>>>(ucnt,ubaseE,usum,NV);
  scan_small_u32<<<1,256,0,stream>>>(usum,49,meta,3);                // meta[3]=M
  emit_verts<<<782,256,0,stream>>>(pos,sdf,ucnt,ubaseE,usum,cntE,bsum,ehi,out,out_size);
  emit_faces<<<3125,256,0,stream>>>(tet,codes,tscan,tsum,meta,ucnt,ubaseE,usum,cntE,bsum,ehi,out,out_size);
}

// Round 4
// 648.602 us; speedup vs baseline: 2.1883x; 1.2678x over previous
//
#include <hip/hip_runtime.h>
#include <cstdint>
#include <cstddef>

#define NV 200000
#define NT 800000
#define ROWS 64
#define NBLK 3125   // 3125*64 = 200000 exactly

typedef unsigned int u32;
typedef unsigned long long u64;
typedef unsigned short ushort_t;

typedef __attribute__((ext_vector_type(8))) _Float16 half8;
typedef __attribute__((ext_vector_type(4))) float f32x4;
#define MFMA16F __builtin_amdgcn_mfma_f32_16x16x32_f16

// ---------------- marching-tets tables ----------------
__constant__ int c_tri[16][6] = {
  {-1,-1,-1,-1,-1,-1},{1,0,2,-1,-1,-1},{4,0,3,-1,-1,-1},{1,4,2,1,3,4},
  {3,1,5,-1,-1,-1},{2,3,0,2,5,3},{1,4,0,1,5,4},{4,2,5,-1,-1,-1},
  {4,5,2,-1,-1,-1},{4,1,0,4,5,1},{3,2,0,3,5,2},{1,3,5,-1,-1,-1},
  {4,1,2,4,3,1},{3,0,4,-1,-1,-1},{2,0,1,-1,-1,-1},{-1,-1,-1,-1,-1,-1}};
__constant__ int c_ntri[16] = {0,1,1,2,1,2,2,1,1,2,2,1,2,1,1,0};
__constant__ int c_be[12] = {0,1,0,2,0,3,1,2,1,3,2,3};

// ---------------- fp16 Dekker 2-way split: x ~= h + m*2^-11, m kept normal ----------------
__device__ __forceinline__ void split2(float x, _Float16& h, _Float16& m){
  h = (_Float16)x;                       // RNE, captures 11 mantissa bits
  const float r = x - (float)h;          // exact (Sterbenz)
  m = (_Float16)(r * 2048.0f);           // next 11 bits, scaled into normal range
}

// ---------------- weight split prep: fp32 W -> 2 fp16 planes, chunk-blocked [c][n][32k] ----------------
// halves offsets: L0 @0 (psz 8192), L1 @16384 (psz 65536), L2 @147456, L3 @278528
__global__ void split_weights(const float* __restrict__ w0, const float* __restrict__ w1,
                              const float* __restrict__ w2, const float* __restrict__ w3,
                              _Float16* __restrict__ wp)
{
  const int idx = blockIdx.x*256 + threadIdx.x;   // 0..204799
  int base, k, n, psz;
  float val;
  if (idx < 8192){                                  // layer0: K=27 padded to 32
    base = 0; psz = 8192; k = idx >> 8; n = idx & 255;
    val = (k < 27) ? w0[k*256 + n] : 0.f;
  } else {
    int r = idx - 8192;
    const int l = r >> 16;                          // 0..2 -> layers 1..3
    r &= 65535;
    k = r >> 8; n = r & 255; psz = 65536;
    base = 16384 + l*131072;
    const float* w = (l==0) ? w1 : (l==1) ? w2 : w3;
    val = w[k*256 + n];
  }
  _Float16 h, m; split2(val, h, m);
  const int c = k >> 5, kk = k & 31;
  const int off = (c*256 + n)*32 + kk;
  wp[base + off] = h;
  wp[base + psz + off] = m;
}

// ---------------- MFMA MLP: block = 64 rows x 256 cols, 512 thr (8 waves x 32 cols) ----------------
// fp16x2 split; products hh -> acc g0, hm'+m'h -> g1; val = g0 + g1*2^-11.
// Layouts (HW-verified): A[m=lane&15][k=(lane>>4)*8+j]; B[n=lane&15][k=...]; C/D col=lane&15,row=(lane>>4)*4+reg.
template<int NC, bool LAST>
__device__ __forceinline__ void layer_run(
    const _Float16* __restrict__ Wl, const float* __restrict__ Bv,
    const float* __restrict__ wfv,
    _Float16 (*Af)[ROWS][264], float (*part)[8],
    int lane, int wv)
{
  const int l15 = lane & 15, q = lane >> 4;
  const int col0 = wv * 32;
  f32x4 g0[4][2], g1[4][2];
#pragma unroll
  for (int i=0;i<4;i++)
#pragma unroll
    for (int j=0;j<2;j++){ g0[i][j] = (f32x4){0.f,0.f,0.f,0.f}; g1[i][j] = (f32x4){0.f,0.f,0.f,0.f}; }

  const _Float16* bp = Wl + (u32)((col0 + l15)*32 + q*8);
  half8 bA[2][2], bB[2][2];

  auto loadB = [&](int c, half8 (*dst)[2]){
#pragma unroll
    for (int p=0;p<2;p++)
#pragma unroll
      for (int nt=0;nt<2;nt++)
        dst[p][nt] = *(const half8*)(bp + (p*NC + c)*8192 + nt*512);
  };
  auto compute = [&](int c, const half8 (*bb)[2]){
#pragma unroll
    for (int mt=0;mt<4;mt++){
      const _Float16* ap = &Af[0][mt*16 + l15][c*32 + q*8];
      const half8 ah = *(const half8*)(ap);
      const half8 am = *(const half8*)(ap + ROWS*264);
#pragma unroll
      for (int nt=0;nt<2;nt++){
        g0[mt][nt] = MFMA16F(ah, bb[0][nt], g0[mt][nt], 0,0,0);   // h*h
        g1[mt][nt] = MFMA16F(ah, bb[1][nt], g1[mt][nt], 0,0,0);   // h*m'
        g1[mt][nt] = MFMA16F(am, bb[0][nt], g1[mt][nt], 0,0,0);   // m'*h
      }
    }
  };

  loadB(0, bA);
  if (NC == 1){
    compute(0, bA);
  } else {
#pragma unroll 1
    for (int ch=0; ch<NC/2; ch++){
      const int c0 = 2*ch;
      loadB(c0+1, bB);
      compute(c0, bA);
      if (c0+2 < NC) loadB(c0+2, bA);
      compute(c0+1, bB);
    }
  }
  __syncthreads();                       // all waves done reading Af this layer

  const float S = 4.8828125e-4f;         // 2^-11
  if (!LAST){
#pragma unroll
    for (int nt=0;nt<2;nt++){
      const int col = col0 + nt*16 + l15;
      const float bias = Bv[col];
#pragma unroll
      for (int mt=0;mt<4;mt++)
#pragma unroll
        for (int reg=0;reg<4;reg++){
          const int row = mt*16 + q*4 + reg;
          const float v = fmaxf(g0[mt][nt][reg] + S*g1[mt][nt][reg] + bias, 0.f);
          _Float16 h,m; split2(v,h,m);
          Af[0][row][col] = h; Af[1][row][col] = m;
        }
    }
  } else {
    float pr[4][4];
#pragma unroll
    for (int mt=0;mt<4;mt++)
#pragma unroll
      for (int reg=0;reg<4;reg++) pr[mt][reg] = 0.f;
#pragma unroll
    for (int nt=0;nt<2;nt++){
      const int col = col0 + nt*16 + l15;
      const float bias = Bv[col];
      const float w = wfv[col];
#pragma unroll
      for (int mt=0;mt<4;mt++)
#pragma unroll
        for (int reg=0;reg<4;reg++)
          pr[mt][reg] += fmaxf(g0[mt][nt][reg] + S*g1[mt][nt][reg] + bias, 0.f) * w;
    }
#pragma unroll
    for (int s=1;s<16;s<<=1)
#pragma unroll
      for (int mt=0;mt<4;mt++)
#pragma unroll
        for (int reg=0;reg<4;reg++)
          pr[mt][reg] += __shfl_xor(pr[mt][reg], s, 64);
    if (l15 == 0){
#pragma unroll
      for (int mt=0;mt<4;mt++)
#pragma unroll
        for (int reg=0;reg<4;reg++)
          part[mt*16 + q*4 + reg][wv] = pr[mt][reg];
    }
  }
  __syncthreads();                       // Af / part writes visible
}

__global__ __launch_bounds__(512,4) void mlp_mfma(
    const float* __restrict__ pos, const _Float16* __restrict__ wp,
    const float* __restrict__ b0, const float* __restrict__ b1,
    const float* __restrict__ b2, const float* __restrict__ b3,
    const float* __restrict__ wf, const float* __restrict__ bf,
    float* __restrict__ sdf)
{
  __shared__ _Float16 Af[2][ROWS][264];    // 67,584 B
  __shared__ float part[ROWS][8];          // 2,048 B -> 69.6 KB total = 2 blocks/CU
  const int tid = threadIdx.x;
  const int lane = tid & 63, wv = tid >> 6;
  const int row0 = blockIdx.x * ROWS;

  // layer0 input: positional encoding + fp16x2 split, K padded 27->32
#pragma unroll
  for (int it=0; it<4; it++){
    const int idx = it*512 + tid;        // 2048 = 64 rows x 32 k
    const int r = idx & 63, f = idx >> 6;
    float val = 0.f;
    if (f < 3){
      val = pos[(row0 + r)*3 + f];
    } else if (f < 27){
      const int g = (f-3)/6, rem = (f-3)%6;
      const int d = rem % 3;
      const float x = pos[(row0 + r)*3 + d];
      const float fr = (float)(1 << g) * 3.14159265358979323846f;
      val = (rem < 3) ? sinf(fr*x) : cosf(fr*x);
    }
    _Float16 h,m; split2(val,h,m);
    Af[0][r][f] = h; Af[1][r][f] = m;
  }
  __syncthreads();

  layer_run<1,false>(wp + 0,      b0, nullptr, Af, part, lane, wv);
  layer_run<8,false>(wp + 16384,  b1, nullptr, Af, part, lane, wv);
  layer_run<8,false>(wp + 147456, b2, nullptr, Af, part, lane, wv);
  layer_run<8,true >(wp + 278528, b3, wf,      Af, part, lane, wv);

  if (tid < ROWS){
    float s = 0.f;
#pragma unroll
    for (int w=0; w<8; w++) s += part[tid][w];
    sdf[row0 + tid] = s + bf[0];
  }
}

// ---------------- block-wide inclusive scan helpers ----------------
__device__ __forceinline__ u32 block_scan_incl_u32(u32 v, u32* sh, int tid){
  sh[tid]=v; __syncthreads();
#pragma unroll
  for (int s=1;s<256;s<<=1){
    const u32 y = (tid>=s) ? sh[tid-s] : 0u;
    __syncthreads();
    sh[tid] += y;
    __syncthreads();
  }
  return sh[tid];
}

// ---------------- tet pass 1: codes, crossing-edge bucket counts, stable (n1,n2) scan ----------------
// 782 blocks x 256 thr x 4 tets = 800,768 (tail guarded)
__global__ void tet_count_scan(const int* __restrict__ tet, const float* __restrict__ sdf,
    unsigned char* __restrict__ codes, u32* __restrict__ tscan, u64* __restrict__ tsum,
    u32* __restrict__ cnt)
{
  __shared__ u32 sh[256];
  const int tid = threadIdx.x;
  const int t0 = blockIdx.x*1024 + tid*4;
  int n1=0, n2=0;
#pragma unroll 1
  for (int i=0;i<4;i++){
    const int t = t0+i;
    int nt = 0;
    if (t < NT){
      tscan[t] = (u32)n1 | ((u32)n2<<16);
      const int4 v = *(const int4*)(&tet[4*t]);
      const int o0 = sdf[v.x] > 0.f;
      const int o1 = sdf[v.y] > 0.f;
      const int o2 = sdf[v.z] > 0.f;
      const int o3 = sdf[v.w] > 0.f;
      const int code = o0 | (o1<<1) | (o2<<2) | (o3<<3);
      codes[t] = (unsigned char)code;
      nt = c_ntri[code];
      if (nt > 0){
        const int vv[4] = {v.x, v.y, v.z, v.w};
        const int oc[4] = {o0,o1,o2,o3};
#pragma unroll
        for (int e=0;e<6;e++){
          const int ia = c_be[2*e], ib = c_be[2*e+1];
          if (oc[ia] != oc[ib]){
            const int p = vv[ia], q = vv[ib];
            const int lo = p<q ? p : q;
            atomicAdd(&cnt[lo], 1u);
          }
        }
      }
    }
    n1 += (nt==1);
    n2 += (nt==2);
  }
  const u32 mytot = (u32)n1 | ((u32)n2<<16);
  const u32 incl = block_scan_incl_u32(mytot, sh, tid);
  const u32 excl = incl - mytot;
#pragma unroll 1
  for (int i=0;i<4;i++){
    const int t = t0+i;
    if (t < NT) tscan[t] += excl;
  }
  if (tid == 255) tsum[blockIdx.x] = (u64)(incl & 0xFFFFu) | ((u64)(incl >> 16) << 32);
}

// 1024-thread single-block u64 scan (nb <= 1024)
__global__ void scan_small_u64(u64* __restrict__ arr, int nb, u32* __restrict__ meta)
{
  __shared__ u64 sh[1024];
  const int tid = threadIdx.x;
  const u64 v = (tid < nb) ? arr[tid] : 0ull;
  sh[tid]=v; __syncthreads();
#pragma unroll
  for (int s=1;s<1024;s<<=1){ const u64 y=(tid>=s)?sh[tid-s]:0ull; __syncthreads(); sh[tid]+=y; __syncthreads(); }
  const u64 incl = sh[tid];
  if (tid < nb) arr[tid] = incl - v;
  if (tid == nb-1){ meta[0]=(u32)(incl & 0xFFFFFFFFull); meta[1]=(u32)(incl>>32); }
}

// 196 blocks x 256 thr x 4 items
__global__ void scan_blocks_u32(const u32* __restrict__ in, u32* __restrict__ out,
                                u32* __restrict__ bsum, int n)
{
  __shared__ u32 sh[256];
  const int tid = threadIdx.x;
  const int base = blockIdx.x*1024 + tid*4;
  u32 v[4]; u32 tot=0;
#pragma unroll
  for (int i=0;i<4;i++){
    const int idx = base+i;
    v[i] = (idx<n) ? in[idx] : 0u;
    tot += v[i];
  }
  const u32 incl = block_scan_incl_u32(tot, sh, tid);
  u32 run = incl - tot;
#pragma unroll
  for (int i=0;i<4;i++){
    const int idx = base+i;
    if (idx<n) out[idx] = run;
    run += v[i];
  }
  if (tid==255) bsum[blockIdx.x] = incl;
}

__global__ void scan_small_u32(u32* __restrict__ arr, int nb, u32* __restrict__ meta, int slot)
{
  __shared__ u32 sh[256];
  const int tid = threadIdx.x;
  const u32 v = (tid<nb)?arr[tid]:0u;
  const u32 incl = block_scan_incl_u32(v, sh, tid);
  if (tid<nb) arr[tid] = incl - v;
  if (tid == nb-1) meta[slot] = incl;
}

// ---------------- scatter crossing-edge his into per-lo buckets ----------------
__global__ void fill_edges(const int* __restrict__ tet, const unsigned char* __restrict__ codes,
    const u32* __restrict__ cntE, const u32* __restrict__ bsum,
    u32* __restrict__ cur, int* __restrict__ ehi, int ecap)
{
  const int t = blockIdx.x*256 + threadIdx.x;
  if (t >= NT) return;
  const int code = codes[t];
  if (c_ntri[code] == 0) return;
  const int4 v = *(const int4*)(&tet[4*t]);
  const int vv[4]={v.x,v.y,v.z,v.w};
  const int oc[4]={code&1,(code>>1)&1,(code>>2)&1,(code>>3)&1};
#pragma unroll
  for (int e=0;e<6;e++){
    const int ia=c_be[2*e], ib=c_be[2*e+1];
    if (oc[ia]!=oc[ib]){
      const int p=vv[ia], q=vv[ib];
      const int lo = p<q?p:q, hi = p<q?q:p;
      const u32 off = bsum[lo>>10] + cntE[lo];
      const u32 slot = atomicAdd(&cur[lo],1u);
      const u32 idx = off + slot;
      if (idx < (u32)ecap) ehi[idx] = hi;
    }
  }
}

// ---------------- per-bucket sort + dedup ----------------
__global__ void sort_dedup(const u32* __restrict__ cnt, const u32* __restrict__ cntE,
    const u32* __restrict__ bsum, int* __restrict__ ehi, u32* __restrict__ ucnt, int ecap)
{
  const int lo = blockIdx.x*256 + threadIdx.x;
  if (lo >= NV) return;
  int n = (int)cnt[lo];
  const u32 off = bsum[lo>>10] + cntE[lo];
  long long rem = (long long)ecap - (long long)off;
  if (rem < 0) rem = 0;
  if ((long long)n > rem) n = (int)rem;
  for (int i=1;i<n;i++){
    const int key = ehi[off+i];
    int j=i-1;
    while (j>=0 && ehi[off+j] > key){ ehi[off+j+1]=ehi[off+j]; j--; }
    ehi[off+j+1]=key;
  }
  int u=0; int prev=-1;
  for (int i=0;i<n;i++){
    const int x = ehi[off+i];
    if (x != prev){ ehi[off+u]=x; u++; prev=x; }
  }
  ucnt[lo]=(u32)u;
}

// ---------------- emit interpolated vertices (id order == jnp.unique lex order) ----------------
__global__ void emit_verts(const float* __restrict__ pos, const float* __restrict__ sdf,
    const u32* __restrict__ ucnt, const u32* __restrict__ ubaseE, const u32* __restrict__ usum,
    const u32* __restrict__ cntE, const u32* __restrict__ bsum,
    const int* __restrict__ ehi, float* __restrict__ out, int out_size)
{
  const int lo = blockIdx.x*256 + threadIdx.x;
  if (lo >= NV) return;
  const int u = (int)ucnt[lo];
  if (u == 0) return;
  const u32 off = bsum[lo>>10] + cntE[lo];
  const u32 idbase = usum[lo>>10] + ubaseE[lo];
  const float s0 = sdf[lo];
  const float p0x = pos[3*lo], p0y = pos[3*lo+1], p0z = pos[3*lo+2];
  for (int j=0;j<u;j++){
    const int hi = ehi[off+j];
    const float s1 = sdf[hi];
    const float d = s0 - s1;
    const float vx = (p0x*(-s1) + pos[3*hi  ]*s0) / d;
    const float vy = (p0y*(-s1) + pos[3*hi+1]*s0) / d;
    const float vz = (p0z*(-s1) + pos[3*hi+2]*s0) / d;
    const long long w = 3ll*(long long)(idbase+(u32)j);
    if (w + 3 <= (long long)out_size){
      out[w]=vx; out[w+1]=vy; out[w+2]=vz;
    }
  }
}

// ---------------- emit faces: all 1-tri tets (tet order), then 2-tri tets ----------------
__global__ void emit_faces(const int* __restrict__ tet, const unsigned char* __restrict__ codes,
    const u32* __restrict__ tscan, const u64* __restrict__ tsumE, const u32* __restrict__ meta,
    const u32* __restrict__ ucnt, const u32* __restrict__ ubaseE, const u32* __restrict__ usum,
    const u32* __restrict__ cntE, const u32* __restrict__ bsum,
    const int* __restrict__ ehi, float* __restrict__ out, int out_size)
{
  const int t = blockIdx.x*256 + threadIdx.x;
  if (t >= NT) return;
  const int code = codes[t];
  const int nt = c_ntri[code];
  if (nt == 0) return;
  const u64 tb = tsumE[t>>10];
  const u32 ts = tscan[t];
  const u32 n1e = (u32)(tb & 0xFFFFFFFFull) + (ts & 0xFFFFu);
  const u32 n2e = (u32)(tb >> 32) + (ts >> 16);
  const u32 N1 = meta[0];
  const u32 M  = meta[3];
  const u32 fb = (nt==1) ? n1e : (N1 + 2u*n2e);
  const int4 v = *(const int4*)(&tet[4*t]);
  const int vv[4]={v.x,v.y,v.z,v.w};
  for (int r=0;r<nt;r++){
    for (int k=0;k<3;k++){
      const int e = c_tri[code][3*r+k];
      const int ia=c_be[2*e], ib=c_be[2*e+1];
      const int p=vv[ia], q=vv[ib];
      const int lo = p<q?p:q, hi = p<q?q:p;
      const u32 off = bsum[lo>>10] + cntE[lo];
      const int u = (int)ucnt[lo];
      int id = -1;
      for (int j=0;j<u;j++){
        if (ehi[off+j]==hi){ id = (int)(usum[lo>>10] + ubaseE[lo]) + j; break; }
      }
      const long long w = 3ll*(long long)M + 3ll*(long long)(fb+(u32)r) + k;
      if (w < (long long)out_size && id >= 0) out[w] = (float)id;
    }
  }
}

// ---------------- launch ----------------
extern "C" void kernel_launch(void* const* d_in, const int* in_sizes, int n_in,
                              void* d_out, int out_size, void* d_ws, size_t ws_size,
                              hipStream_t stream)
{
  (void)in_sizes; (void)n_in;
  const float* pos = (const float*)d_in[0];
  const int*   tet = (const int*)d_in[1];
  const float* w0 = (const float*)d_in[2];
  const float* b0 = (const float*)d_in[3];
  const float* w1 = (const float*)d_in[4];
  const float* b1 = (const float*)d_in[5];
  const float* w2 = (const float*)d_in[6];
  const float* b2 = (const float*)d_in[7];
  const float* w3 = (const float*)d_in[8];
  const float* b3 = (const float*)d_in[9];
  const float* wf = (const float*)d_in[10];
  const float* bf = (const float*)d_in[11];
  float* out = (float*)d_out;
  char* ws = (char*)d_ws;

  float*         sdf   = (float*)(ws + 0);               // 200000 f32
  unsigned char* codes = (unsigned char*)(ws + 800000);  // 800000 u8
  u32* cnt    = (u32*)(ws + 1600000);                    // 200000 u32
  u32* cntE   = (u32*)(ws + 2400000);
  u32* ucnt   = (u32*)(ws + 3200000);
  u32* ubaseE = (u32*)(ws + 4000000);
  u32* cur    = (u32*)(ws + 4800000);
  u32* bsum   = (u32*)(ws + 5600000);                    // 1024 B (196 u32 used)
  u32* usum   = (u32*)(ws + 5601024);                    // 1024 B
  u32* meta   = (u32*)(ws + 5602048);                    // 64 B
  u64* tsum   = (u64*)(ws + 5602112);                    // 8192 B (782 u64 used)
  u32* tscan  = (u32*)(ws + 5610304);                    // 3200000 B
  _Float16* wp = (_Float16*)(ws + 8810304);              // 409600 halves = 819200 B
  int* ehi    = (int*)(ws + 9629504);
  const long long avail = (long long)ws_size - 9629504ll;
  const int ecap = avail > 0 ? (int)((avail/4 < 500000ll) ? avail/4 : 500000ll) : 0;

  hipMemsetAsync(cnt, 0, 800000, stream);
  hipMemsetAsync(cur, 0, 800000, stream);

  split_weights<<<800,256,0,stream>>>(w0,w1,w2,w3,wp);
  mlp_mfma<<<NBLK,512,0,stream>>>(pos,wp,b0,b1,b2,b3,wf,bf,sdf);

  tet_count_scan<<<782,256,0,stream>>>(tet,sdf,codes,tscan,tsum,cnt);
  scan_small_u64<<<1,1024,0,stream>>>(tsum,782,meta);                // meta[0]=N1, meta[1]=N2
  scan_blocks_u32<<<196,256,0,stream>>>(cnt,cntE,bsum,NV);
  scan_small_u32<<<1,256,0,stream>>>(bsum,196,meta,2);               // meta[2]=E
  fill_edges<<<3125,256,0,stream>>>(tet,codes,cntE,bsum,cur,ehi,ecap);
  sort_dedup<<<782,256,0,stream>>>(cnt,cntE,bsum,ehi,ucnt,ecap);
  scan_blocks_u32<<<196,256,0,stream>>>(ucnt,ubaseE,usum,NV);
  scan_small_u32<<<1,256,0,stream>>>(usum,196,meta,3);               // meta[3]=M
  emit_verts<<<782,256,0,stream>>>(pos,sdf,ucnt,ubaseE,usum,cntE,bsum,ehi,out,out_size);
  emit_faces<<<3125,256,0,stream>>>(tet,codes,tscan,tsum,meta,ucnt,ubaseE,usum,cntE,bsum,ehi,out,out_size);
}